// Round 20
// baseline (72.961 us; speedup 1.0000x reference)
//
#include <hip/hip_runtime.h>

#define HH    1024
#define WW    1024
#define KS    15
#define PAD   7
#define CELL  256
#define BX    64            // x-width per block (4 waves x 16)
#define TROWS 142           // tile rows (128-row strip + 2*PAD)
#define TCOLS 80            // staged halves per row (160B rows)
#define NITER 16            // 2 strips x 8 patches
#define CHN   18            // 2 strips x 9 chunks (16 rows each; tail 14)
#define AWS_CELL_BYTES (KS * 1024)   // 15 fragments x 1KB

typedef _Float16     f16x8 __attribute__((ext_vector_type(8)));
typedef _Float16     f16x4 __attribute__((ext_vector_type(4)));
typedef float        f32x4 __attribute__((ext_vector_type(4)));
typedef unsigned int u32x4 __attribute__((ext_vector_type(4)));

// Barrier with LDS ordering only (no vmcnt(0) drain).
static __device__ __forceinline__ void light_barrier() {
    asm volatile("s_waitcnt lgkmcnt(0)\n\ts_barrier" ::: "memory");
}

// dst[cc] = src[(cc+1) & 15] within each 16-lane row.
// gfx9 DPP row_ror:N semantics: dst[n] = src[(n-N) & 15]; we need +1 -> N=15.
// (R19 used row_ror:1 = 0x121 -> mirror direction -> absmax 1.12 FAIL.)
static __device__ __forceinline__ u32x4 ror1(u32x4 v) {
    u32x4 r;
    #pragma unroll
    for (int d = 0; d < 4; ++d)
        r[d] = (unsigned)__builtin_amdgcn_update_dpp(
                   0, (int)v[d], 0x12F, 0xF, 0xF, false);
    return r;
}

// ---- prep: materialize normalized Toeplitz A fragments per cell into d_ws ----
__global__ __launch_bounds__(256) void pb_prep_kernel(
    const float* __restrict__ kern, unsigned int* __restrict__ aws)
{
    const int cell = blockIdx.x;           // cj*4+ci
    const int tid  = threadIdx.x;
    const int lane = tid & 63;
    const float* kp = kern + cell * (KS * KS);

    float s = 0.f;
    #pragma unroll
    for (int i = 0; i < 4; ++i) {
        int t = lane + 64 * i;
        s += (t < KS * KS) ? kp[t] : 0.f;
    }
    #pragma unroll
    for (int m = 1; m < 64; m <<= 1) s += __shfl_xor(s, m, 64);
    const float inv = 1.0f / (s + 1e-12f);

    const int i  = tid >> 4;               // x-position (A row)
    const int k2 = tid & 15;               // half-pair index
    unsigned int* wp = aws + cell * (AWS_CELL_BYTES / 4) + tid;

    for (int dy = 0; dy < KS; ++dy) {
        float v0 = 0.f, v1 = 0.f;
        int dx0 = 2 * k2 - i - 1;          // A[i][k] = kh[k-i-1]
        int dx1 = dx0 + 1;
        if (dx0 >= 0 && dx0 < KS) v0 = kp[dy * KS + dx0] * inv;
        if (dx1 >= 0 && dx1 < KS) v1 = kp[dy * KS + dx1] * inv;
        f16x4 h; h[0] = (_Float16)v0; h[1] = (_Float16)v1; h[2] = 0; h[3] = 0;
        unsigned long long u = __builtin_bit_cast(unsigned long long, h);
        wp[dy * 256] = (unsigned int)u;
    }
}

// ---- main: R15 rolling 256-row block + REGISTER-ROTATION fragments.
// fragment(dy+1)[cc] = fragment(dy)[cc+1]: read only F0 (rows 16jp+cc) and
// F1 (rows 16jp+16+cc) per patch (prefetched one iter early); build each
// fragment(dy) with DPP rotate + select  b[cc] = (cc+dy>=16) ? F1r : F0r
// (both = row 16jp+dy+cc; F1 source lanes 14,15 never consumed).
// LDS reads/patch: 15 -> 2. Write schedule: write chunk t+4 at iter t,
// issue t+6, prologue stages 0..3 — prefetched chunks committed >=1 barrier
// earlier; concurrent writes disjoint (verified per-t incl. strip seam).
__global__ __launch_bounds__(256, 3) void pb_mfma_kernel(
    const float* __restrict__ x,
    const unsigned int* __restrict__ aws,
    float* __restrict__ out)
{
    __shared__ __align__(16) _Float16 s_tile[TROWS * TCOLS];   // 22720 B

    const int tid  = threadIdx.x;
    const int lane = tid & 63;
    const int w    = tid >> 6;           // wave id: x sub-block
    const int g    = lane >> 4;          // k-group 0..3
    const int cc   = lane & 15;          // B-col (image-row) index

    const int bx0 = blockIdx.x * BX;
    const int ci  = blockIdx.x >> 2;     // cell col
    const int cj  = blockIdx.y;          // cell row
    const int bc  = blockIdx.z;          // plane (b*c)

    const int cellx0 = ci * CELL;
    const int celly0 = cj * CELL, celly1 = celly0 + CELL - 1;

    const float* plane = x + (size_t)bc * HH * WW;

    // ---- A fragments: 15 coalesced dwordx4 loads, pinned resident (R8) ----
    const u32x4* ap = (const u32x4*)(aws + (cj * 4 + ci) * (AWS_CELL_BYTES / 4))
                      + cc * 4 + g;
    u32x4 af[KS];
    #pragma unroll
    for (int dy = 0; dy < KS; ++dy) af[dy] = ap[dy * 64];
    #pragma unroll
    for (int dy = 0; dy < KS; ++dy) asm volatile("" : "+v"(af[dy]));

    // ---- staging helpers (16-row chunks, 320 groups; tail 280) ----
    auto stage_addr = [&](int strip, int lc, int idx) -> const float* {
        int r20  = idx / 20;
        int c4   = idx - r20 * 20;
        int row  = lc * 16 + r20;                       // tile row
        int gy   = min(max(celly0 + strip * 128 - PAD + row, celly0), celly1);
        int gx0  = bx0 - 8 + 4 * c4;
        int gx0c = min(max(gx0, cellx0), cellx0 + CELL - 4);
        return plane + (size_t)gy * WW + gx0c;
    };
    auto write_group = [&](int lc, int idx, float4 v) {
        int r20 = idx / 20;
        int c4  = idx - r20 * 20;
        int row = lc * 16 + r20;
        int gx0 = bx0 - 8 + 4 * c4;
        bool lo = gx0 <  cellx0;
        bool hi = gx0 >  cellx0 + CELL - 4;
        float e0 = hi ? v.w : v.x;
        float e1 = lo ? v.x : (hi ? v.w : v.y);
        float e2 = lo ? v.x : (hi ? v.w : v.z);
        float e3 = lo ? v.x : v.w;
        f16x4 h;
        h[0] = (_Float16)e0; h[1] = (_Float16)e1;
        h[2] = (_Float16)e2; h[3] = (_Float16)e3;
        *(f16x4*)(s_tile + row * TCOLS + 4 * c4) = h;   // ds_write_b64
    };
    auto issue_chunk = [&](int c, float4& v0, float4& v1, bool& h1) {
        int strip = c >= 9;
        int lc    = c - 9 * strip;
        int ng    = (lc == 8) ? 280 : 320;
        v0 = *(const float4*)stage_addr(strip, lc, tid);
        h1 = 256 + tid < ng;
        if (h1) v1 = *(const float4*)stage_addr(strip, lc, 256 + tid);
    };
    auto write_chunk = [&](int c, float4 v0, float4 v1, bool h1) {
        int strip = c >= 9;
        int lc    = c - 9 * strip;
        (void)strip;
        write_group(lc, tid, v0);
        if (h1) write_group(lc, 256 + tid, v1);
    };

    // ---- prologue: stage chunks 0..3; issue 4,5 as 2-deep pending ----
    {
        float4 a0, a1, b0, b1, c0, c1, d0, d1; bool ha, hb, hc, hd;
        issue_chunk(0, a0, a1, ha);
        issue_chunk(1, b0, b1, hb);
        issue_chunk(2, c0, c1, hc);
        issue_chunk(3, d0, d1, hd);
        write_chunk(0, a0, a1, ha);
        write_chunk(1, b0, b1, hb);
        write_chunk(2, c0, c1, hc);
        write_chunk(3, d0, d1, hd);
    }
    float4 pA0, pA1, pB0, pB1; bool hA1, hB1;
    issue_chunk(4, pA0, pA1, hA1);
    issue_chunk(5, pB0, pB1, hB1);
    light_barrier();

    // ---- initial fragments for t=0 (chunks 0,1 staged) ----
    const _Float16* bbase = s_tile + cc * TCOLS + w * 16 + g * 8;
    u32x4 F0 = *(const u32x4*)(bbase);                  // rows cc
    u32x4 F1 = *(const u32x4*)(bbase + 16 * TCOLS);     // rows 16+cc
    float* oplane = out + (size_t)bc * HH * WW;

    #pragma unroll
    for (int t = 0; t < NITER; ++t) {
        const int strip = t >> 3;
        const int jpl   = t & 7;

        // issue chunk t+6 (global loads; landed at iter t+2)
        float4 n0 = {0,0,0,0}, n1 = {0,0,0,0}; bool hn1 = false;
        if (t + 6 < CHN) issue_chunk(t + 6, n0, n1, hn1);

        // prefetch next patch's fragments (their chunks committed <= t-1)
        u32x4 F0n = F0, F1n = F1;
        if (t + 1 < NITER) {
            const int jn = (t + 1) & 7;
            F0n = *(const u32x4*)(bbase + (16 * jn) * TCOLS);
            if (jn == 7) {
                int r1 = min(128 + cc, TROWS - 1);      // clamp; F1 src lanes 14,15 unused
                F1n = *(const u32x4*)(s_tile + r1 * TCOLS + w * 16 + g * 8);
            } else {
                F1n = *(const u32x4*)(bbase + (16 * jn + 16) * TCOLS);
            }
        }

        // compute patch t: dy=0 uses F0; dy>=1 via rotate+select
        f32x4 acc0 = {0.f, 0.f, 0.f, 0.f};
        f32x4 acc1 = {0.f, 0.f, 0.f, 0.f};
        u32x4 F0r = F0, F1r = F1;
        acc0 = __builtin_amdgcn_mfma_f32_16x16x32_f16(
                   __builtin_bit_cast(f16x8, af[0]),
                   __builtin_bit_cast(f16x8, F0r), acc0, 0, 0, 0);
        #pragma unroll
        for (int dy = 1; dy < KS; ++dy) {
            F0r = ror1(F0r);
            F1r = ror1(F1r);
            u32x4 bb;
            #pragma unroll
            for (int d = 0; d < 4; ++d)
                bb[d] = (cc + dy >= 16) ? F1r[d] : F0r[d];
            if (dy & 1)
                acc1 = __builtin_amdgcn_mfma_f32_16x16x32_f16(
                           __builtin_bit_cast(f16x8, af[dy]),
                           __builtin_bit_cast(f16x8, bb), acc1, 0, 0, 0);
            else
                acc0 = __builtin_amdgcn_mfma_f32_16x16x32_f16(
                           __builtin_bit_cast(f16x8, af[dy]),
                           __builtin_bit_cast(f16x8, bb), acc0, 0, 0, 0);
        }
        f32x4 r = acc0 + acc1;
        // D: col=lane&15 (image row), row=4*(lane>>4)+e (x position)
        float* op = oplane
                  + (size_t)(celly0 + strip * 128 + 16 * jpl + cc) * WW
                  + bx0 + 16 * w + 4 * g;
        *(f32x4*)op = r;   // rides across light barriers, no drain

        // land pending-oldest chunk t+4 (disjoint from all reads this iter)
        if (t + 4 < CHN) write_chunk(t + 4, pA0, pA1, hA1);
        light_barrier();

        pA0 = pB0; pA1 = pB1; hA1 = hB1;
        pB0 = n0;  pB1 = n1;  hB1 = hn1;
        F0 = F0n; F1 = F1n;
    }
}

extern "C" void kernel_launch(void* const* d_in, const int* in_sizes, int n_in,
                              void* d_out, int out_size, void* d_ws, size_t ws_size,
                              hipStream_t stream) {
    (void)in_sizes; (void)n_in; (void)ws_size; (void)out_size;
    const float* x    = (const float*)d_in[0];
    const float* kern = (const float*)d_in[1];
    float* out        = (float*)d_out;
    unsigned int* aws = (unsigned int*)d_ws;   // 16 cells x 15 KiB = 240 KiB

    pb_prep_kernel<<<16, 256, 0, stream>>>(kern, aws);
    dim3 grid(WW / BX, 4, 8 * 3);   // 16 x-strips, 4 cell-rows, 24 planes
    pb_mfma_kernel<<<grid, 256, 0, stream>>>(x, aws, out);
}

// Round 21
// 56.137 us; speedup vs baseline: 1.2997x; 1.2997x over previous
//
#include <hip/hip_runtime.h>

#define HH    1024
#define WW    1024
#define KS    15
#define PAD   7
#define CELL  256
#define BX    64            // x-width per block (4 waves x 16)
#define TROWS 142           // tile rows (128-row strip + 2*PAD)
#define TCOLS 80            // staged halves per row (160B rows)
#define NITER 16            // 2 strips x 8 patches
#define CHN   18            // 2 strips x 9 chunks (8 full + 14-row tail each)
#define AWS_CELL_BYTES (KS * 1024)   // 15 fragments x 1KB

typedef _Float16     f16x8 __attribute__((ext_vector_type(8)));
typedef _Float16     f16x4 __attribute__((ext_vector_type(4)));
typedef float        f32x4 __attribute__((ext_vector_type(4)));
typedef unsigned int u32x4 __attribute__((ext_vector_type(4)));

// Barrier with LDS ordering only (no vmcnt(0) drain): output stores and
// prefetch loads ride across; ds_write data dependency gives precise vmcnt.
static __device__ __forceinline__ void light_barrier() {
    asm volatile("s_waitcnt lgkmcnt(0)\n\ts_barrier" ::: "memory");
}

// ---- prep: materialize normalized Toeplitz A fragments per cell into d_ws ----
__global__ __launch_bounds__(256) void pb_prep_kernel(
    const float* __restrict__ kern, unsigned int* __restrict__ aws)
{
    const int cell = blockIdx.x;           // cj*4+ci
    const int tid  = threadIdx.x;
    const int lane = tid & 63;
    const float* kp = kern + cell * (KS * KS);

    float s = 0.f;
    #pragma unroll
    for (int i = 0; i < 4; ++i) {
        int t = lane + 64 * i;
        s += (t < KS * KS) ? kp[t] : 0.f;
    }
    #pragma unroll
    for (int m = 1; m < 64; m <<= 1) s += __shfl_xor(s, m, 64);
    const float inv = 1.0f / (s + 1e-12f);

    const int i  = tid >> 4;               // x-position (A row)
    const int k2 = tid & 15;               // half-pair index
    unsigned int* wp = aws + cell * (AWS_CELL_BYTES / 4) + tid;

    for (int dy = 0; dy < KS; ++dy) {
        float v0 = 0.f, v1 = 0.f;
        int dx0 = 2 * k2 - i - 1;          // A[i][k] = kh[k-i-1]
        int dx1 = dx0 + 1;
        if (dx0 >= 0 && dx0 < KS) v0 = kp[dy * KS + dx0] * inv;
        if (dx1 >= 0 && dx1 < KS) v1 = kp[dy * KS + dx1] * inv;
        f16x4 h; h[0] = (_Float16)v0; h[1] = (_Float16)v1; h[2] = 0; h[3] = 0;
        unsigned long long u = __builtin_bit_cast(unsigned long long, h);
        wp[dy * 256] = (unsigned int)u;
    }
}

// ---- main: R15 (best, 56.0 us) + T5 s_setprio around the MFMA cluster.
// R20 proved the LDS fragment re-reads are NOT the serial term (replacing
// them with serial DPP rotation: 73 us, VALU 64%). R15's plateau = register-
// capped concurrency (af-resident 132 regs -> 3 waves/SIMD) x phase-coupled
// loop. Resident blocks ARE at different phases; setprio(1) during the
// MFMA+ds_read cluster makes the scheduler prefer compute-phase waves over
// staging-issue waves (T5 regime: independent blocks, measured +4-7%).
__global__ __launch_bounds__(256, 4) void pb_mfma_kernel(
    const float* __restrict__ x,
    const unsigned int* __restrict__ aws,
    float* __restrict__ out)
{
    __shared__ __align__(16) _Float16 s_tile[TROWS * TCOLS];   // 22720 B

    const int tid  = threadIdx.x;
    const int lane = tid & 63;
    const int w    = tid >> 6;           // wave id: x sub-block
    const int g    = lane >> 4;          // k-group 0..3
    const int cc   = lane & 15;          // A-row / B-col index

    const int bx0 = blockIdx.x * BX;
    const int ci  = blockIdx.x >> 2;     // cell col
    const int cj  = blockIdx.y;          // cell row
    const int bc  = blockIdx.z;          // plane (b*c)

    const int cellx0 = ci * CELL;
    const int celly0 = cj * CELL, celly1 = celly0 + CELL - 1;

    const float* plane = x + (size_t)bc * HH * WW;

    // ---- A fragments: 15 coalesced dwordx4 loads, pinned resident (R8) ----
    const u32x4* ap = (const u32x4*)(aws + (cj * 4 + ci) * (AWS_CELL_BYTES / 4))
                      + cc * 4 + g;
    u32x4 af[KS];
    #pragma unroll
    for (int dy = 0; dy < KS; ++dy) af[dy] = ap[dy * 64];
    #pragma unroll
    for (int dy = 0; dy < KS; ++dy) asm volatile("" : "+v"(af[dy]));

    // ---- staging helpers ----
    auto stage_addr = [&](int strip, int lc, int idx) -> const float* {
        int r20  = idx / 20;
        int c4   = idx - r20 * 20;
        int row  = lc * 16 + r20;                       // tile row 0..141
        int gy   = min(max(celly0 + strip * 128 - PAD + row, celly0), celly1);
        int gx0  = bx0 - 8 + 4 * c4;
        int gx0c = min(max(gx0, cellx0), cellx0 + CELL - 4);
        return plane + (size_t)gy * WW + gx0c;
    };
    auto write_group = [&](int lc, int idx, float4 v) {
        int r20 = idx / 20;
        int c4  = idx - r20 * 20;
        int row = lc * 16 + r20;
        int gx0 = bx0 - 8 + 4 * c4;
        bool lo = gx0 <  cellx0;
        bool hi = gx0 >  cellx0 + CELL - 4;
        float e0 = hi ? v.w : v.x;
        float e1 = lo ? v.x : (hi ? v.w : v.y);
        float e2 = lo ? v.x : (hi ? v.w : v.z);
        float e3 = lo ? v.x : v.w;
        f16x4 h;
        h[0] = (_Float16)e0; h[1] = (_Float16)e1;
        h[2] = (_Float16)e2; h[3] = (_Float16)e3;
        *(f16x4*)(s_tile + row * TCOLS + 4 * c4) = h;   // ds_write_b64
    };
    auto issue_chunk = [&](int c, float4& v0, float4& v1, bool& h1) {
        int strip = c >= 9;
        int lc    = c - 9 * strip;
        int ng    = (lc == 8) ? 280 : 320;
        v0 = *(const float4*)stage_addr(strip, lc, tid);
        h1 = 256 + tid < ng;
        if (h1) v1 = *(const float4*)stage_addr(strip, lc, 256 + tid);
    };
    auto write_chunk = [&](int c, float4 v0, float4 v1, bool h1) {
        int strip = c >= 9;
        int lc    = c - 9 * strip;
        (void)strip;
        write_group(lc, tid, v0);
        if (h1) write_group(lc, 256 + tid, v1);
    };

    // ---- prologue: stage chunks 0..2; issue 3,4 as 2-deep pending ----
    {
        float4 a0, a1, b0, b1, c0, c1; bool ha1, hb1, hc1;
        issue_chunk(0, a0, a1, ha1);
        issue_chunk(1, b0, b1, hb1);
        issue_chunk(2, c0, c1, hc1);
        write_chunk(0, a0, a1, ha1);
        write_chunk(1, b0, b1, hb1);
        write_chunk(2, c0, c1, hc1);
    }
    float4 pA0, pA1, pB0, pB1; bool hA1, hB1;
    issue_chunk(3, pA0, pA1, hA1);
    issue_chunk(4, pB0, pB1, hB1);
    light_barrier();

    // ---- rolling main loop: 16 iterations (2 strips x 8 patches) ----
    const _Float16* bbase = s_tile + cc * TCOLS + w * 16 + g * 8;
    float* oplane = out + (size_t)bc * HH * WW;

    #pragma unroll
    for (int t = 0; t < NITER; ++t) {
        const int strip = t >> 3;
        const int jpl   = t & 7;

        // issue chunk t+5 (written at iter t+2: two iterations of cover)
        float4 n0 = {0,0,0,0}, n1 = {0,0,0,0}; bool hn1 = false;
        if (t + 5 < CHN) issue_chunk(t + 5, n0, n1, hn1);

        // compute patch: reads tile rows 16*jpl .. 16*jpl+30
        // T5: boost priority through the ds_read+MFMA cluster so compute-
        // phase waves preempt staging-issue waves of co-resident blocks.
        __builtin_amdgcn_s_setprio(1);
        f32x4 acc0 = {0.f, 0.f, 0.f, 0.f};
        f32x4 acc1 = {0.f, 0.f, 0.f, 0.f};
        #pragma unroll
        for (int dy = 0; dy < KS; ++dy) {
            f16x8 b = *(const f16x8*)(bbase + (16 * jpl + dy) * TCOLS);
            if (dy & 1)
                acc1 = __builtin_amdgcn_mfma_f32_16x16x32_f16(
                           __builtin_bit_cast(f16x8, af[dy]), b, acc1, 0, 0, 0);
            else
                acc0 = __builtin_amdgcn_mfma_f32_16x16x32_f16(
                           __builtin_bit_cast(f16x8, af[dy]), b, acc0, 0, 0, 0);
        }
        __builtin_amdgcn_s_setprio(0);
        f32x4 r = acc0 + acc1;
        // D: col=lane&15 (image row), row=4*(lane>>4)+e (x position)
        float* op = oplane
                  + (size_t)(celly0 + strip * 128 + 16 * jpl + cc) * WW
                  + bx0 + 16 * w + 4 * g;
        *(f32x4*)op = r;   // rides across light barriers, no drain

        // land pending-oldest chunk t+3 (rows disjoint from patch t's reads)
        if (t + 3 < CHN) write_chunk(t + 3, pA0, pA1, hA1);
        light_barrier();

        // rotate pending
        pA0 = pB0; pA1 = pB1; hA1 = hB1;
        pB0 = n0;  pB1 = n1;  hB1 = hn1;
    }
}

extern "C" void kernel_launch(void* const* d_in, const int* in_sizes, int n_in,
                              void* d_out, int out_size, void* d_ws, size_t ws_size,
                              hipStream_t stream) {
    (void)in_sizes; (void)n_in; (void)ws_size; (void)out_size;
    const float* x    = (const float*)d_in[0];
    const float* kern = (const float*)d_in[1];
    float* out        = (float*)d_out;
    unsigned int* aws = (unsigned int*)d_ws;   // 16 cells x 15 KiB = 240 KiB

    pb_prep_kernel<<<16, 256, 0, stream>>>(kern, aws);
    dim3 grid(WW / BX, 4, 8 * 3);   // 16 x-strips, 4 cell-rows, 24 planes
    pb_mfma_kernel<<<grid, 256, 0, stream>>>(x, aws, out);
}

// Round 22
// 48.258 us; speedup vs baseline: 1.5119x; 1.1633x over previous
//
#include <hip/hip_runtime.h>

#define HH    1024
#define WW    1024
#define KS    15
#define PAD   7
#define CELL  256
#define BX    64            // x-width per block (4 waves x 16)
#define TROWS 142           // tile rows (128-row strip + 2*PAD)
#define TCOLS 80            // staged halves per row (160B rows)
#define NITER 16            // 2 strips x 8 patches
#define CHN   18            // 2 strips x 9 chunks (8 full + 14-row tail each)
#define NWG   (16 * 4 * 24) // 1536 blocks, % 8 == 0 -> simple bijective swizzle
#define AWS_CELL_BYTES (KS * 1024)   // 15 fragments x 1KB

typedef _Float16     f16x8 __attribute__((ext_vector_type(8)));
typedef _Float16     f16x4 __attribute__((ext_vector_type(4)));
typedef float        f32x4 __attribute__((ext_vector_type(4)));
typedef unsigned int u32x4 __attribute__((ext_vector_type(4)));

// Barrier with LDS ordering only (no vmcnt(0) drain): output stores and
// prefetch loads ride across; ds_write data dependency gives precise vmcnt.
static __device__ __forceinline__ void light_barrier() {
    asm volatile("s_waitcnt lgkmcnt(0)\n\ts_barrier" ::: "memory");
}

// ---- prep: materialize normalized Toeplitz A fragments per cell into d_ws ----
__global__ __launch_bounds__(256) void pb_prep_kernel(
    const float* __restrict__ kern, unsigned int* __restrict__ aws)
{
    const int cell = blockIdx.x;           // cj*4+ci
    const int tid  = threadIdx.x;
    const int lane = tid & 63;
    const float* kp = kern + cell * (KS * KS);

    float s = 0.f;
    #pragma unroll
    for (int i = 0; i < 4; ++i) {
        int t = lane + 64 * i;
        s += (t < KS * KS) ? kp[t] : 0.f;
    }
    #pragma unroll
    for (int m = 1; m < 64; m <<= 1) s += __shfl_xor(s, m, 64);
    const float inv = 1.0f / (s + 1e-12f);

    const int i  = tid >> 4;               // x-position (A row)
    const int k2 = tid & 15;               // half-pair index
    unsigned int* wp = aws + cell * (AWS_CELL_BYTES / 4) + tid;

    for (int dy = 0; dy < KS; ++dy) {
        float v0 = 0.f, v1 = 0.f;
        int dx0 = 2 * k2 - i - 1;          // A[i][k] = kh[k-i-1]
        int dx1 = dx0 + 1;
        if (dx0 >= 0 && dx0 < KS) v0 = kp[dy * KS + dx0] * inv;
        if (dx1 >= 0 && dx1 < KS) v1 = kp[dy * KS + dx1] * inv;
        f16x4 h; h[0] = (_Float16)v0; h[1] = (_Float16)v1; h[2] = 0; h[3] = 0;
        unsigned long long u = __builtin_bit_cast(unsigned long long, h);
        wp[dy * 256] = (unsigned int)u;
    }
}

// ---- main: R15/R21 rolling 256-row block + T1 XCD-aware block swizzle.
// 1D grid of 1536; sw = (bid%8)*192 + bid/8 gives each XCD 192 contiguous
// blocks = 3 complete planes: per-cell A-table (read by 96 blocks) and
// x-adjacent halo panels become XCD-local L2 hits instead of cross-XCD
// re-fetches. Kernel body identical to R21 (best, 56.0-56.1 us).
__global__ __launch_bounds__(256, 4) void pb_mfma_kernel(
    const float* __restrict__ x,
    const unsigned int* __restrict__ aws,
    float* __restrict__ out)
{
    __shared__ __align__(16) _Float16 s_tile[TROWS * TCOLS];   // 22720 B

    const int tid  = threadIdx.x;
    const int lane = tid & 63;
    const int w    = tid >> 6;           // wave id: x sub-block
    const int g    = lane >> 4;          // k-group 0..3
    const int cc   = lane & 15;          // A-row / B-col index

    // T1 swizzle: bijective for NWG % 8 == 0
    const int bid = blockIdx.x;
    const int sw  = (bid & 7) * (NWG / 8) + (bid >> 3);
    const int sbx = sw & 15;             // 16 x-strips
    const int sby = (sw >> 4) & 3;       // 4 cell-rows
    const int sbz = sw >> 6;             // 24 planes

    const int bx0 = sbx * BX;
    const int ci  = sbx >> 2;            // cell col
    const int cj  = sby;                 // cell row
    const int bc  = sbz;                 // plane (b*c)

    const int cellx0 = ci * CELL;
    const int celly0 = cj * CELL, celly1 = celly0 + CELL - 1;

    const float* plane = x + (size_t)bc * HH * WW;

    // ---- A fragments: 15 coalesced dwordx4 loads, pinned resident (R8) ----
    const u32x4* ap = (const u32x4*)(aws + (cj * 4 + ci) * (AWS_CELL_BYTES / 4))
                      + cc * 4 + g;
    u32x4 af[KS];
    #pragma unroll
    for (int dy = 0; dy < KS; ++dy) af[dy] = ap[dy * 64];
    #pragma unroll
    for (int dy = 0; dy < KS; ++dy) asm volatile("" : "+v"(af[dy]));

    // ---- staging helpers ----
    auto stage_addr = [&](int strip, int lc, int idx) -> const float* {
        int r20  = idx / 20;
        int c4   = idx - r20 * 20;
        int row  = lc * 16 + r20;                       // tile row 0..141
        int gy   = min(max(celly0 + strip * 128 - PAD + row, celly0), celly1);
        int gx0  = bx0 - 8 + 4 * c4;
        int gx0c = min(max(gx0, cellx0), cellx0 + CELL - 4);
        return plane + (size_t)gy * WW + gx0c;
    };
    auto write_group = [&](int lc, int idx, float4 v) {
        int r20 = idx / 20;
        int c4  = idx - r20 * 20;
        int row = lc * 16 + r20;
        int gx0 = bx0 - 8 + 4 * c4;
        bool lo = gx0 <  cellx0;
        bool hi = gx0 >  cellx0 + CELL - 4;
        float e0 = hi ? v.w : v.x;
        float e1 = lo ? v.x : (hi ? v.w : v.y);
        float e2 = lo ? v.x : (hi ? v.w : v.z);
        float e3 = lo ? v.x : v.w;
        f16x4 h;
        h[0] = (_Float16)e0; h[1] = (_Float16)e1;
        h[2] = (_Float16)e2; h[3] = (_Float16)e3;
        *(f16x4*)(s_tile + row * TCOLS + 4 * c4) = h;   // ds_write_b64
    };
    auto issue_chunk = [&](int c, float4& v0, float4& v1, bool& h1) {
        int strip = c >= 9;
        int lc    = c - 9 * strip;
        int ng    = (lc == 8) ? 280 : 320;
        v0 = *(const float4*)stage_addr(strip, lc, tid);
        h1 = 256 + tid < ng;
        if (h1) v1 = *(const float4*)stage_addr(strip, lc, 256 + tid);
    };
    auto write_chunk = [&](int c, float4 v0, float4 v1, bool h1) {
        int strip = c >= 9;
        int lc    = c - 9 * strip;
        (void)strip;
        write_group(lc, tid, v0);
        if (h1) write_group(lc, 256 + tid, v1);
    };

    // ---- prologue: stage chunks 0..2; issue 3,4 as 2-deep pending ----
    {
        float4 a0, a1, b0, b1, c0, c1; bool ha1, hb1, hc1;
        issue_chunk(0, a0, a1, ha1);
        issue_chunk(1, b0, b1, hb1);
        issue_chunk(2, c0, c1, hc1);
        write_chunk(0, a0, a1, ha1);
        write_chunk(1, b0, b1, hb1);
        write_chunk(2, c0, c1, hc1);
    }
    float4 pA0, pA1, pB0, pB1; bool hA1, hB1;
    issue_chunk(3, pA0, pA1, hA1);
    issue_chunk(4, pB0, pB1, hB1);
    light_barrier();

    // ---- rolling main loop: 16 iterations (2 strips x 8 patches) ----
    const _Float16* bbase = s_tile + cc * TCOLS + w * 16 + g * 8;
    float* oplane = out + (size_t)bc * HH * WW;

    #pragma unroll
    for (int t = 0; t < NITER; ++t) {
        const int strip = t >> 3;
        const int jpl   = t & 7;

        // issue chunk t+5 (written at iter t+2: two iterations of cover)
        float4 n0 = {0,0,0,0}, n1 = {0,0,0,0}; bool hn1 = false;
        if (t + 5 < CHN) issue_chunk(t + 5, n0, n1, hn1);

        // compute patch: reads tile rows 16*jpl .. 16*jpl+30
        __builtin_amdgcn_s_setprio(1);
        f32x4 acc0 = {0.f, 0.f, 0.f, 0.f};
        f32x4 acc1 = {0.f, 0.f, 0.f, 0.f};
        #pragma unroll
        for (int dy = 0; dy < KS; ++dy) {
            f16x8 b = *(const f16x8*)(bbase + (16 * jpl + dy) * TCOLS);
            if (dy & 1)
                acc1 = __builtin_amdgcn_mfma_f32_16x16x32_f16(
                           __builtin_bit_cast(f16x8, af[dy]), b, acc1, 0, 0, 0);
            else
                acc0 = __builtin_amdgcn_mfma_f32_16x16x32_f16(
                           __builtin_bit_cast(f16x8, af[dy]), b, acc0, 0, 0, 0);
        }
        __builtin_amdgcn_s_setprio(0);
        f32x4 r = acc0 + acc1;
        // D: col=lane&15 (image row), row=4*(lane>>4)+e (x position)
        float* op = oplane
                  + (size_t)(celly0 + strip * 128 + 16 * jpl + cc) * WW
                  + bx0 + 16 * w + 4 * g;
        *(f32x4*)op = r;   // rides across light barriers, no drain

        // land pending-oldest chunk t+3 (rows disjoint from patch t's reads)
        if (t + 3 < CHN) write_chunk(t + 3, pA0, pA1, hA1);
        light_barrier();

        // rotate pending
        pA0 = pB0; pA1 = pB1; hA1 = hB1;
        pB0 = n0;  pB1 = n1;  hB1 = hn1;
    }
}

extern "C" void kernel_launch(void* const* d_in, const int* in_sizes, int n_in,
                              void* d_out, int out_size, void* d_ws, size_t ws_size,
                              hipStream_t stream) {
    (void)in_sizes; (void)n_in; (void)ws_size; (void)out_size;
    const float* x    = (const float*)d_in[0];
    const float* kern = (const float*)d_in[1];
    float* out        = (float*)d_out;
    unsigned int* aws = (unsigned int*)d_ws;   // 16 cells x 15 KiB = 240 KiB

    pb_prep_kernel<<<16, 256, 0, stream>>>(kern, aws);
    pb_mfma_kernel<<<NWG, 256, 0, stream>>>(x, aws, out);   // 1D grid, swizzled inside
}